// Round 2
// baseline (562.369 us; speedup 1.0000x reference)
//
#include <hip/hip_runtime.h>
#include <hip/hip_bf16.h>
#include <math.h>

typedef __bf16 bf16_t;
typedef __bf16 bf16x4 __attribute__((ext_vector_type(4)));
typedef __bf16 bf16x8 __attribute__((ext_vector_type(8)));
typedef float f32x4 __attribute__((ext_vector_type(4)));

#define NB 2
#define NH 16
#define SEQ 2048
#define HD 64
#define DMODEL 1024
#define QK_SCALE 0.125f
#define LOG2E 1.44269504088896340f
#define INV_2PI 0.15915494309189535f

__device__ __forceinline__ bf16_t to_bf16(float x) { return (bf16_t)x; }
#define MFMA16 __builtin_amdgcn_mfma_f32_16x16x32_bf16

// ---------------------------------------------------------------------------
// K1: RoPE(q,k) + cast to bf16 + layout packs. HW trig (revolutions + fract).
//  qrT[b][h][d][s]  (scaled by QK_SCALE)  -> A-operand of qt^T GEMM
//  krN[b][h][s][d]                        -> A-operand of S^T  (keys as M)
//  vT [b][h][d][s]                        -> B-operand of PV
// ---------------------------------------------------------------------------
__global__ __launch_bounds__(256) void k1_rope_pack(
    const float* __restrict__ q, const float* __restrict__ k, const float* __restrict__ v,
    bf16_t* __restrict__ qrT, bf16_t* __restrict__ krN, bf16_t* __restrict__ vT)
{
  __shared__ bf16_t tile[64][65];   // odd pitch: conflict-free transpose
  const int tid = threadIdx.x;
  const int blk = blockIdx.x;        // bh*32 + s_tile
  const int st = blk & 31;
  const int bh = blk >> 5;
  const int s0 = st * 64;

  const size_t base_sd = ((size_t)bh * SEQ + s0) * HD;
  const float* qb = q + base_sd;
  const float* kb = k + base_sd;
  const float* vb = v + base_sd;
  bf16_t* qrTb = qrT + (size_t)bh * HD * SEQ;
  bf16_t* krNb = krN + base_sd;
  bf16_t* vTb  = vT  + (size_t)bh * HD * SEQ;

  #pragma unroll
  for (int pp = 0; pp < 2; ++pp) {
    int idx = pp * 256 + tid;          // 0..511
    int sr = idx >> 3;                 // row 0..63
    int j0 = (idx & 7) * 4;            // pair group 0,4,...,28
    float4 q1 = *(const float4*)&qb[sr*HD + j0];
    float4 q2 = *(const float4*)&qb[sr*HD + j0 + 32];
    float4 ka = *(const float4*)&kb[sr*HD + j0];
    float4 kc = *(const float4*)&kb[sr*HD + j0 + 32];
    float q1a[4] = {q1.x, q1.y, q1.z, q1.w};
    float q2a[4] = {q2.x, q2.y, q2.z, q2.w};
    float kaa[4] = {ka.x, ka.y, ka.z, ka.w};
    float kca[4] = {kc.x, kc.y, kc.z, kc.w};
    bf16x4 kr1, kr2;
    #pragma unroll
    for (int t = 0; t < 4; ++t) {
      int j = j0 + t;
      float freq = __builtin_amdgcn_exp2f(-(float)j * (13.287712379549449f / 32.0f));
      float ang = (float)(s0 + sr) * freq;
      float rev = ang * INV_2PI;
      rev = rev - floorf(rev);
      float c  = __builtin_amdgcn_cosf(rev);
      float sn = __builtin_amdgcn_sinf(rev);
      tile[sr][j]      = to_bf16((q1a[t]*c - q2a[t]*sn) * QK_SCALE);
      tile[sr][j + 32] = to_bf16((q2a[t]*c + q1a[t]*sn) * QK_SCALE);
      kr1[t] = to_bf16(kaa[t]*c - kca[t]*sn);
      kr2[t] = to_bf16(kca[t]*c + kaa[t]*sn);
    }
    *(bf16x4*)&krNb[sr*HD + j0]      = kr1;
    *(bf16x4*)&krNb[sr*HD + j0 + 32] = kr2;
  }
  __syncthreads();
  #pragma unroll
  for (int c = 0; c < 2; ++c) {
    int id = c*256 + tid;
    int d = id >> 3;
    int sc = (id & 7) * 8;
    bf16x8 vec;
    #pragma unroll
    for (int i = 0; i < 8; ++i) vec[i] = tile[sc + i][d];
    *(bf16x8*)&qrTb[(size_t)d * SEQ + s0 + sc] = vec;
  }
  __syncthreads();
  #pragma unroll
  for (int c = 0; c < 4; ++c) {
    int id = c*256 + tid;
    int sr = id >> 4;
    int c4 = (id & 15) * 4;
    float4 v4 = *(const float4*)&vb[sr*HD + c4];
    tile[sr][c4+0] = to_bf16(v4.x);
    tile[sr][c4+1] = to_bf16(v4.y);
    tile[sr][c4+2] = to_bf16(v4.z);
    tile[sr][c4+3] = to_bf16(v4.w);
  }
  __syncthreads();
  #pragma unroll
  for (int c = 0; c < 2; ++c) {
    int id = c*256 + tid;
    int d = id >> 3;
    int sc = (id & 7) * 8;
    bf16x8 vec;
    #pragma unroll
    for (int i = 0; i < 8; ++i) vec[i] = tile[sc + i][d];
    *(bf16x8*)&vTb[(size_t)d * SEQ + s0 + sc] = vec;
  }
}

// ---------------------------------------------------------------------------
// K2: qt^T = qr^T x W^T per head.  BK=64, register-prefetch pipeline.
// XCD-chunked block swizzle (same-head blocks share qrT panel in one L2).
// ---------------------------------------------------------------------------
__global__ __launch_bounds__(256) void k2_qt_gemm(
    const float* __restrict__ Wm,      // [NH][SEQ][SEQ] fp32
    const bf16_t* __restrict__ qrT,    // [b][h][d][s]
    bf16_t* __restrict__ qtT)          // [b][h][d][s]  (x LOG2E)
{
  __shared__ __align__(16) bf16_t A_lds[2][64*72];   // qr^T tiles (d x k), pad 8
  __shared__ __align__(16) bf16_t B_lds[64*72];      // W tile (q_out x k)
  const int tid = threadIdx.x;
  const int blk = (blockIdx.x & 7) * 64 + (blockIdx.x >> 3);   // h*32 + ntile
  const int n0 = (blk & 31) * 64;
  const int h = blk >> 5;
  const int wave = tid >> 6, lane = tid & 63;
  const int l15 = lane & 15, quad = lane >> 4;
  const int rs = tid >> 2, cs = (tid & 3) * 16;      // staging: row 0..63, col 0..48

  const float* Wh = Wm + (size_t)h * SEQ * SEQ + (size_t)n0 * SEQ;
  const bf16_t* A0 = qrT + ((size_t)h * HD + rs) * SEQ;
  const bf16_t* A1 = qrT + (((size_t)NH + h) * HD + rs) * SEQ;

  f32x4 acc[2][4] = {};
  float4 wreg[4];
  bf16x8 areg[2][2];

  // preload kb=0
  #pragma unroll
  for (int i = 0; i < 4; ++i) wreg[i] = *(const float4*)&Wh[(size_t)rs*SEQ + cs + i*4];
  #pragma unroll
  for (int i = 0; i < 2; ++i) {
    areg[0][i] = *(const bf16x8*)&A0[cs + i*8];
    areg[1][i] = *(const bf16x8*)&A1[cs + i*8];
  }

  for (int it = 0; it < SEQ/64; ++it) {
    if (it) __syncthreads();
    #pragma unroll
    for (int i = 0; i < 2; ++i) {
      *(bf16x8*)&A_lds[0][rs*72 + cs + i*8] = areg[0][i];
      *(bf16x8*)&A_lds[1][rs*72 + cs + i*8] = areg[1][i];
      bf16x8 wb;
      float4 wa = wreg[i*2], wc = wreg[i*2+1];
      wb[0]=to_bf16(wa.x); wb[1]=to_bf16(wa.y); wb[2]=to_bf16(wa.z); wb[3]=to_bf16(wa.w);
      wb[4]=to_bf16(wc.x); wb[5]=to_bf16(wc.y); wb[6]=to_bf16(wc.z); wb[7]=to_bf16(wc.w);
      *(bf16x8*)&B_lds[rs*72 + cs + i*8] = wb;
    }
    __syncthreads();
    if (it + 1 < SEQ/64) {
      int kb = (it + 1) * 64;
      #pragma unroll
      for (int i = 0; i < 4; ++i) wreg[i] = *(const float4*)&Wh[(size_t)rs*SEQ + kb + cs + i*4];
      #pragma unroll
      for (int i = 0; i < 2; ++i) {
        areg[0][i] = *(const bf16x8*)&A0[kb + cs + i*8];
        areg[1][i] = *(const bf16x8*)&A1[kb + cs + i*8];
      }
    }
    #pragma unroll
    for (int kc = 0; kc < 2; ++kc) {
      const int off = kc*32 + quad*8;
      bf16x8 bfr[4];
      #pragma unroll
      for (int nt = 0; nt < 4; ++nt)
        bfr[nt] = *(const bf16x8*)&B_lds[(nt*16 + l15)*72 + off];
      #pragma unroll
      for (int b2 = 0; b2 < 2; ++b2) {
        bf16x8 af = *(const bf16x8*)&A_lds[b2][(wave*16 + l15)*72 + off];
        #pragma unroll
        for (int nt = 0; nt < 4; ++nt)
          acc[b2][nt] = MFMA16(af, bfr[nt], acc[b2][nt], 0, 0, 0);
      }
    }
  }
  #pragma unroll
  for (int b2 = 0; b2 < 2; ++b2)
    #pragma unroll
    for (int nt = 0; nt < 4; ++nt)
      #pragma unroll
      for (int r = 0; r < 4; ++r) {
        int d = wave*16 + quad*4 + r;
        qtT[(((size_t)b2*NH + h)*HD + d)*SEQ + n0 + nt*16 + l15] =
            to_bf16(acc[b2][nt][r] * LOG2E);
      }
}

// ---------------------------------------------------------------------------
// K3 (Round 2): barrier-free attention. K/V fragments loaded DIRECTLY from
// global (L2-resident: 512 KB per bh, ~2 MB per XCD with chunked swizzle) —
// the LDS staging + 2 barriers/tile were pure overhead (Common-mistake #7).
// Register double-buffer (unroll-2, static names). P round-trip stays in
// per-wave-private LDS (lgkmcnt only, no barriers anywhere in the k-loop).
// ---------------------------------------------------------------------------
__global__ __launch_bounds__(256, 2) void k3_flash(
    const bf16_t* __restrict__ qtT,    // [b][h][d][s] (x LOG2E, x QK_SCALE)
    const bf16_t* __restrict__ krN,    // [b][h][s][d]
    const bf16_t* __restrict__ vT,     // [b][h][d][s]
    bf16_t* __restrict__ ctx)          // [b][s][DMODEL]
{
  __shared__ __align__(16) bf16_t P_lds[4][16*72];   // per-wave P^T (q x key)
  const int tid = threadIdx.x;
  // XCD-chunked swizzle: each XCD sees 4 consecutive bh (16 q-tiles each)
  const int blk = (blockIdx.x & 7) * 64 + (blockIdx.x >> 3);   // bh*16 + q-tile(128)
  const int qt = blk & 15;
  const int bh = blk >> 4;
  const int h = bh & 15, b = bh >> 4;
  const int wave = tid >> 6, lane = tid & 63;
  const int l15 = lane & 15, quad = lane >> 4;
  const int qw = qt*128 + wave*32;   // wave's 32 q rows

  const bf16_t* qtb = qtT + (size_t)bh * HD * SEQ;
  // per-lane fragment base pointers (row = l15, 16B chunk at quad*8)
  const bf16_t* krb = krN + (size_t)bh * SEQ * HD + (size_t)l15 * HD + quad*8;
  const bf16_t* vtb = vT  + (size_t)bh * HD * SEQ + (size_t)l15 * SEQ + quad*8;

  // Q B-fragments (k=d contiguous via stride-SEQ gather; once per block)
  bf16x8 Qf[2][2];
  #pragma unroll
  for (int g = 0; g < 2; ++g)
    #pragma unroll
    for (int c = 0; c < 2; ++c)
      #pragma unroll
      for (int j = 0; j < 8; ++j)
        Qf[g][c][j] = qtb[(size_t)(c*32 + quad*8 + j)*SEQ + qw + g*16 + l15];

  bf16x8 ones;
  #pragma unroll
  for (int j = 0; j < 8; ++j) ones[j] = to_bf16(1.0f);

  f32x4 O[2][4] = {};
  f32x4 L[2] = {};

  bf16x8 akA[4][2], bvA[4][2], akB[4][2], bvB[4][2];

  // fragment loads for key-tile KT: identical indices to the old LDS reads,
  // source = global.  ak[nt][c] = K[kt*64+nt*16+l15][c*32+quad*8 ..+7]
  //                   bv[nt][c] = V^T[nt*16+l15][kt*64+c*32+quad*8 ..+7]
#define LOADT(AK, BV, KT) do {                                            \
    const bf16_t* kp_ = krb + (size_t)(KT) * 64 * HD;                     \
    const bf16_t* vp_ = vtb + (size_t)(KT) * 64;                          \
    _Pragma("unroll")                                                     \
    for (int nt_ = 0; nt_ < 4; ++nt_) {                                   \
      _Pragma("unroll")                                                   \
      for (int c_ = 0; c_ < 2; ++c_) {                                    \
        AK[nt_][c_] = *(const bf16x8*)&kp_[nt_*16*HD + c_*32];            \
        BV[nt_][c_] = *(const bf16x8*)&vp_[(size_t)nt_*16*SEQ + c_*32];   \
      }                                                                   \
    }                                                                     \
  } while (0)

#define COMPUTE(AK, BV) do {                                              \
    _Pragma("unroll")                                                     \
    for (int g = 0; g < 2; ++g) {                                         \
      f32x4 s_[4] = {};                                                   \
      __builtin_amdgcn_s_setprio(1);                                      \
      _Pragma("unroll")                                                   \
      for (int nt = 0; nt < 4; ++nt) {                                    \
        s_[nt] = MFMA16(AK[nt][0], Qf[g][0], s_[nt], 0, 0, 0);            \
        s_[nt] = MFMA16(AK[nt][1], Qf[g][1], s_[nt], 0, 0, 0);            \
      }                                                                   \
      __builtin_amdgcn_s_setprio(0);                                      \
      _Pragma("unroll")                                                   \
      for (int nt = 0; nt < 4; ++nt) {                                    \
        bf16x4 pk;                                                        \
        _Pragma("unroll")                                                 \
        for (int r = 0; r < 4; ++r)                                       \
          pk[r] = to_bf16(__builtin_amdgcn_exp2f(s_[nt][r]));             \
        *(bf16x4*)&P_lds[wave][l15*72 + nt*16 + quad*4] = pk;             \
      }                                                                   \
      bf16x8 ap0 = *(const bf16x8*)&P_lds[wave][l15*72 + quad*8];         \
      bf16x8 ap1 = *(const bf16x8*)&P_lds[wave][l15*72 + 32 + quad*8];    \
      __builtin_amdgcn_s_setprio(1);                                      \
      _Pragma("unroll")                                                   \
      for (int nt = 0; nt < 4; ++nt) {                                    \
        O[g][nt] = MFMA16(ap0, BV[nt][0], O[g][nt], 0, 0, 0);             \
        O[g][nt] = MFMA16(ap1, BV[nt][1], O[g][nt], 0, 0, 0);             \
      }                                                                   \
      L[g] = MFMA16(ap0, ones, L[g], 0, 0, 0);                            \
      L[g] = MFMA16(ap1, ones, L[g], 0, 0, 0);                            \
      __builtin_amdgcn_s_setprio(0);                                      \
    }                                                                     \
  } while (0)

  LOADT(akA, bvA, 0);
  for (int kt = 0; kt < 32; kt += 2) {
    LOADT(akB, bvB, kt + 1);        // prefetch odd tile (kt+1 <= 31 always)
    COMPUTE(akA, bvA);              // tile kt
    if (kt + 2 < 32) LOADT(akA, bvA, kt + 2);   // prefetch next even tile
    COMPUTE(akB, bvB);              // tile kt+1
  }
#undef LOADT
#undef COMPUTE

  #pragma unroll
  for (int g = 0; g < 2; ++g)
    #pragma unroll
    for (int nt = 0; nt < 4; ++nt)
      #pragma unroll
      for (int r = 0; r < 4; ++r) {
        int qrow = qw + g*16 + quad*4 + r;
        float o = O[g][nt][r] / L[g][r];
        ctx[((size_t)b*SEQ + qrow)*DMODEL + h*HD + nt*16 + l15] = to_bf16(o);
      }
}

// ---------------------------------------------------------------------------
// K4: out = ctx @ out_w^T + bias. m-tile 128 x n-tile 64, BK=64, prefetch.
// ---------------------------------------------------------------------------
__global__ __launch_bounds__(256) void k4_proj(
    const bf16_t* __restrict__ ctx,    // [NB*SEQ][DMODEL] bf16
    const float* __restrict__ w,       // [DMODEL][DMODEL] fp32
    const float* __restrict__ bias,
    float* __restrict__ out)
{
  __shared__ __align__(16) bf16_t A_lds[128*72];
  __shared__ __align__(16) bf16_t B_lds[64*72];
  const int tid = threadIdx.x;
  const int blk = blockIdx.x;        // mt*16 + ntile
  const int n0 = (blk & 15) * 64;
  const int m0 = (blk >> 4) * 128;
  const int wave = tid >> 6, lane = tid & 63;
  const int l15 = lane & 15, quad = lane >> 4;
  const int ra = tid >> 1, ca = (tid & 1) * 32;     // A staging: 128 rows x 32
  const int rs = tid >> 2, cs = (tid & 3) * 16;     // W staging: 64 rows x 16

  f32x4 acc[2][4] = {};
  bf16x8 areg[4];
  float4 wreg[4];

  #pragma unroll
  for (int i = 0; i < 4; ++i) {
    areg[i] = *(const bf16x8*)&ctx[(size_t)(m0 + ra)*DMODEL + ca + i*8];
    wreg[i] = *(const float4*)&w[(size_t)(n0 + rs)*DMODEL + cs + i*4];
  }

  for (int it = 0; it < DMODEL/64; ++it) {
    if (it) __syncthreads();
    #pragma unroll
    for (int i = 0; i < 4; ++i)
      *(bf16x8*)&A_lds[ra*72 + ca + i*8] = areg[i];
    #pragma unroll
    for (int i = 0; i < 2; ++i) {
      bf16x8 wb;
      float4 wa = wreg[i*2], wc = wreg[i*2+1];
      wb[0]=to_bf16(wa.x); wb[1]=to_bf16(wa.y); wb[2]=to_bf16(wa.z); wb[3]=to_bf16(wa.w);
      wb[4]=to_bf16(wc.x); wb[5]=to_bf16(wc.y); wb[6]=to_bf16(wc.z); wb[7]=to_bf16(wc.w);
      *(bf16x8*)&B_lds[rs*72 + cs + i*8] = wb;
    }
    __syncthreads();
    if (it + 1 < DMODEL/64) {
      int kb = (it + 1) * 64;
      #pragma unroll
      for (int i = 0; i < 4; ++i) {
        areg[i] = *(const bf16x8*)&ctx[(size_t)(m0 + ra)*DMODEL + kb + ca + i*8];
        wreg[i] = *(const float4*)&w[(size_t)(n0 + rs)*DMODEL + kb + cs + i*4];
      }
    }
    #pragma unroll
    for (int kc = 0; kc < 2; ++kc) {
      const int off = kc*32 + quad*8;
      bf16x8 bfr[4];
      #pragma unroll
      for (int nt = 0; nt < 4; ++nt)
        bfr[nt] = *(const bf16x8*)&B_lds[(nt*16 + l15)*72 + off];
      #pragma unroll
      for (int g = 0; g < 2; ++g) {
        bf16x8 af = *(const bf16x8*)&A_lds[(wave*32 + g*16 + l15)*72 + off];
        #pragma unroll
        for (int nt = 0; nt < 4; ++nt)
          acc[g][nt] = MFMA16(af, bfr[nt], acc[g][nt], 0, 0, 0);
      }
    }
  }
  #pragma unroll
  for (int nt = 0; nt < 4; ++nt) {
    float bb = bias[n0 + nt*16 + l15];
    #pragma unroll
    for (int g = 0; g < 2; ++g)
      #pragma unroll
      for (int r = 0; r < 4; ++r)
        out[(size_t)(m0 + wave*32 + g*16 + quad*4 + r)*DMODEL + n0 + nt*16 + l15] =
            acc[g][nt][r] + bb;
  }
}

extern "C" void kernel_launch(void* const* d_in, const int* in_sizes, int n_in,
                              void* d_out, int out_size, void* d_ws, size_t ws_size,
                              hipStream_t stream)
{
  const float* q     = (const float*)d_in[0];
  const float* k     = (const float*)d_in[1];
  const float* v     = (const float*)d_in[2];
  const float* mask  = (const float*)d_in[3];
  const float* out_w = (const float*)d_in[4];
  const float* out_b = (const float*)d_in[5];
  float* out = (float*)d_out;

  const size_t elems = (size_t)NB * NH * SEQ * HD;
  bf16_t* qrT = (bf16_t*)d_ws;
  bf16_t* krN = qrT + elems;
  bf16_t* vT  = krN + elems;
  bf16_t* qtT = vT  + elems;
  bf16_t* ctx = qtT + elems;

  k1_rope_pack<<<dim3(NB*NH*(SEQ/64)), dim3(256), 0, stream>>>(q, k, v, qrT, krN, vT);
  k2_qt_gemm <<<dim3(NH*(SEQ/64)),     dim3(256), 0, stream>>>(mask, qrT, qtT);
  k3_flash   <<<dim3(NB*NH*(SEQ/128)), dim3(256), 0, stream>>>(qtT, krN, vT, ctx);
  k4_proj    <<<dim3((NB*SEQ/128)*(DMODEL/64)), dim3(256), 0, stream>>>(ctx, out_w, out_b, out);
}

// Round 3
// 491.231 us; speedup vs baseline: 1.1448x; 1.1448x over previous
//
#include <hip/hip_runtime.h>
#include <hip/hip_bf16.h>
#include <math.h>

typedef __bf16 bf16_t;
typedef __bf16 bf16x4 __attribute__((ext_vector_type(4)));
typedef __bf16 bf16x8 __attribute__((ext_vector_type(8)));
typedef float f32x4 __attribute__((ext_vector_type(4)));

#define NB 2
#define NH 16
#define SEQ 2048
#define HD 64
#define DMODEL 1024
#define QK_SCALE 0.125f
#define LOG2E 1.44269504088896340f
#define INV_2PI 0.15915494309189535f

__device__ __forceinline__ bf16_t to_bf16(float x) { return (bf16_t)x; }
#define MFMA16 __builtin_amdgcn_mfma_f32_16x16x32_bf16

// ---------------------------------------------------------------------------
// K1: RoPE(q,k) + cast to bf16 + layout packs. HW trig (revolutions + fract).
// ---------------------------------------------------------------------------
__global__ __launch_bounds__(256) void k1_rope_pack(
    const float* __restrict__ q, const float* __restrict__ k, const float* __restrict__ v,
    bf16_t* __restrict__ qrT, bf16_t* __restrict__ krN, bf16_t* __restrict__ vT)
{
  __shared__ bf16_t tile[64][65];   // odd pitch: conflict-free transpose
  const int tid = threadIdx.x;
  const int blk = blockIdx.x;        // bh*32 + s_tile
  const int st = blk & 31;
  const int bh = blk >> 5;
  const int s0 = st * 64;

  const size_t base_sd = ((size_t)bh * SEQ + s0) * HD;
  const float* qb = q + base_sd;
  const float* kb = k + base_sd;
  const float* vb = v + base_sd;
  bf16_t* qrTb = qrT + (size_t)bh * HD * SEQ;
  bf16_t* krNb = krN + base_sd;
  bf16_t* vTb  = vT  + (size_t)bh * HD * SEQ;

  #pragma unroll
  for (int pp = 0; pp < 2; ++pp) {
    int idx = pp * 256 + tid;          // 0..511
    int sr = idx >> 3;                 // row 0..63
    int j0 = (idx & 7) * 4;            // pair group 0,4,...,28
    float4 q1 = *(const float4*)&qb[sr*HD + j0];
    float4 q2 = *(const float4*)&qb[sr*HD + j0 + 32];
    float4 ka = *(const float4*)&kb[sr*HD + j0];
    float4 kc = *(const float4*)&kb[sr*HD + j0 + 32];
    float q1a[4] = {q1.x, q1.y, q1.z, q1.w};
    float q2a[4] = {q2.x, q2.y, q2.z, q2.w};
    float kaa[4] = {ka.x, ka.y, ka.z, ka.w};
    float kca[4] = {kc.x, kc.y, kc.z, kc.w};
    bf16x4 kr1, kr2;
    #pragma unroll
    for (int t = 0; t < 4; ++t) {
      int j = j0 + t;
      float freq = __builtin_amdgcn_exp2f(-(float)j * (13.287712379549449f / 32.0f));
      float ang = (float)(s0 + sr) * freq;
      float rev = ang * INV_2PI;
      rev = rev - floorf(rev);
      float c  = __builtin_amdgcn_cosf(rev);
      float sn = __builtin_amdgcn_sinf(rev);
      tile[sr][j]      = to_bf16((q1a[t]*c - q2a[t]*sn) * QK_SCALE);
      tile[sr][j + 32] = to_bf16((q2a[t]*c + q1a[t]*sn) * QK_SCALE);
      kr1[t] = to_bf16(kaa[t]*c - kca[t]*sn);
      kr2[t] = to_bf16(kca[t]*c + kaa[t]*sn);
    }
    *(bf16x4*)&krNb[sr*HD + j0]      = kr1;
    *(bf16x4*)&krNb[sr*HD + j0 + 32] = kr2;
  }
  __syncthreads();
  #pragma unroll
  for (int c = 0; c < 2; ++c) {
    int id = c*256 + tid;
    int d = id >> 3;
    int sc = (id & 7) * 8;
    bf16x8 vec;
    #pragma unroll
    for (int i = 0; i < 8; ++i) vec[i] = tile[sc + i][d];
    *(bf16x8*)&qrTb[(size_t)d * SEQ + s0 + sc] = vec;
  }
  __syncthreads();
  #pragma unroll
  for (int c = 0; c < 4; ++c) {
    int id = c*256 + tid;
    int sr = id >> 4;
    int c4 = (id & 15) * 4;
    float4 v4 = *(const float4*)&vb[sr*HD + c4];
    tile[sr][c4+0] = to_bf16(v4.x);
    tile[sr][c4+1] = to_bf16(v4.y);
    tile[sr][c4+2] = to_bf16(v4.z);
    tile[sr][c4+3] = to_bf16(v4.w);
  }
  __syncthreads();
  #pragma unroll
  for (int c = 0; c < 2; ++c) {
    int id = c*256 + tid;
    int d = id >> 3;
    int sc = (id & 7) * 8;
    bf16x8 vec;
    #pragma unroll
    for (int i = 0; i < 8; ++i) vec[i] = tile[sc + i][d];
    *(bf16x8*)&vTb[(size_t)d * SEQ + s0 + sc] = vec;
  }
}

// ---------------------------------------------------------------------------
// K2: qt^T = qr^T x W^T per head.  BK=64, register-prefetch pipeline.
// XCD-chunked block swizzle (same-head blocks share qrT panel in one L2).
// ---------------------------------------------------------------------------
__global__ __launch_bounds__(256) void k2_qt_gemm(
    const float* __restrict__ Wm,      // [NH][SEQ][SEQ] fp32
    const bf16_t* __restrict__ qrT,    // [b][h][d][s]
    bf16_t* __restrict__ qtT)          // [b][h][d][s]  (x LOG2E)
{
  __shared__ __align__(16) bf16_t A_lds[2][64*72];   // qr^T tiles (d x k), pad 8
  __shared__ __align__(16) bf16_t B_lds[64*72];      // W tile (q_out x k)
  const int tid = threadIdx.x;
  const int blk = (blockIdx.x & 7) * 64 + (blockIdx.x >> 3);   // h*32 + ntile
  const int n0 = (blk & 31) * 64;
  const int h = blk >> 5;
  const int wave = tid >> 6, lane = tid & 63;
  const int l15 = lane & 15, quad = lane >> 4;
  const int rs = tid >> 2, cs = (tid & 3) * 16;      // staging: row 0..63, col 0..48

  const float* Wh = Wm + (size_t)h * SEQ * SEQ + (size_t)n0 * SEQ;
  const bf16_t* A0 = qrT + ((size_t)h * HD + rs) * SEQ;
  const bf16_t* A1 = qrT + (((size_t)NH + h) * HD + rs) * SEQ;

  f32x4 acc[2][4] = {};
  float4 wreg[4];
  bf16x8 areg[2][2];

  // preload kb=0
  #pragma unroll
  for (int i = 0; i < 4; ++i) wreg[i] = *(const float4*)&Wh[(size_t)rs*SEQ + cs + i*4];
  #pragma unroll
  for (int i = 0; i < 2; ++i) {
    areg[0][i] = *(const bf16x8*)&A0[cs + i*8];
    areg[1][i] = *(const bf16x8*)&A1[cs + i*8];
  }

  for (int it = 0; it < SEQ/64; ++it) {
    if (it) __syncthreads();
    #pragma unroll
    for (int i = 0; i < 2; ++i) {
      *(bf16x8*)&A_lds[0][rs*72 + cs + i*8] = areg[0][i];
      *(bf16x8*)&A_lds[1][rs*72 + cs + i*8] = areg[1][i];
      bf16x8 wb;
      float4 wa = wreg[i*2], wc = wreg[i*2+1];
      wb[0]=to_bf16(wa.x); wb[1]=to_bf16(wa.y); wb[2]=to_bf16(wa.z); wb[3]=to_bf16(wa.w);
      wb[4]=to_bf16(wc.x); wb[5]=to_bf16(wc.y); wb[6]=to_bf16(wc.z); wb[7]=to_bf16(wc.w);
      *(bf16x8*)&B_lds[rs*72 + cs + i*8] = wb;
    }
    __syncthreads();
    if (it + 1 < SEQ/64) {
      int kb = (it + 1) * 64;
      #pragma unroll
      for (int i = 0; i < 4; ++i) wreg[i] = *(const float4*)&Wh[(size_t)rs*SEQ + kb + cs + i*4];
      #pragma unroll
      for (int i = 0; i < 2; ++i) {
        areg[0][i] = *(const bf16x8*)&A0[kb + cs + i*8];
        areg[1][i] = *(const bf16x8*)&A1[kb + cs + i*8];
      }
    }
    #pragma unroll
    for (int kc = 0; kc < 2; ++kc) {
      const int off = kc*32 + quad*8;
      bf16x8 bfr[4];
      #pragma unroll
      for (int nt = 0; nt < 4; ++nt)
        bfr[nt] = *(const bf16x8*)&B_lds[(nt*16 + l15)*72 + off];
      #pragma unroll
      for (int b2 = 0; b2 < 2; ++b2) {
        bf16x8 af = *(const bf16x8*)&A_lds[b2][(wave*16 + l15)*72 + off];
        #pragma unroll
        for (int nt = 0; nt < 4; ++nt)
          acc[b2][nt] = MFMA16(af, bfr[nt], acc[b2][nt], 0, 0, 0);
      }
    }
  }
  #pragma unroll
  for (int b2 = 0; b2 < 2; ++b2)
    #pragma unroll
    for (int nt = 0; nt < 4; ++nt)
      #pragma unroll
      for (int r = 0; r < 4; ++r) {
        int d = wave*16 + quad*4 + r;
        qtT[(((size_t)b2*NH + h)*HD + d)*SEQ + n0 + nt*16 + l15] =
            to_bf16(acc[b2][nt][r] * LOG2E);
      }
}

// ---------------------------------------------------------------------------
// K3 (Round 3): back to LDS-staged K/V (R1 structure, known-good), but
// DOUBLE-BUFFERED -> ONE barrier per k-tile instead of two. Stage-write of
// tile kt+1 goes into buf[cur^1] AFTER the compute phase, so the global
// prefetch has the whole MFMA+exp2 phase to land and the write overlaps the
// compute tail. Race-free: writes to buf[cur^1] in iter kt vs reads of that
// buffer in iter kt-1 are separated by the end-of-(kt-1) barrier.
// ---------------------------------------------------------------------------
__global__ __launch_bounds__(256, 2) void k3_flash(
    const bf16_t* __restrict__ qtT,    // [b][h][d][s] (x LOG2E, x QK_SCALE)
    const bf16_t* __restrict__ krN,    // [b][h][s][d]
    const bf16_t* __restrict__ vT,     // [b][h][d][s]
    bf16_t* __restrict__ ctx)          // [b][s][DMODEL]
{
  __shared__ __align__(16) bf16_t K_lds[2][64*72];
  __shared__ __align__(16) bf16_t V_lds[2][64*72];
  __shared__ __align__(16) bf16_t P_lds[4][16*72];   // per-wave P^T (q x key)
  const int tid = threadIdx.x;
  // XCD-chunked swizzle: each XCD sees 4 consecutive bh (16 q-tiles each)
  const int blk = (blockIdx.x & 7) * 64 + (blockIdx.x >> 3);   // bh*16 + q-tile(128)
  const int qt = blk & 15;
  const int bh = blk >> 4;
  const int h = bh & 15, b = bh >> 4;
  const int wave = tid >> 6, lane = tid & 63;
  const int l15 = lane & 15, quad = lane >> 4;
  const int qw = qt*128 + wave*32;   // wave's 32 q rows
  const int srow = tid >> 3, sch = (tid & 7) * 8;  // staging coords

  const bf16_t* qtb = qtT + (size_t)bh * HD * SEQ;
  const bf16_t* krb = krN + (size_t)bh * SEQ * HD;
  const bf16_t* vtb = vT  + (size_t)bh * HD * SEQ;

  // Q B-fragments (k=d contiguous via stride-SEQ gather; once per block)
  bf16x8 Qf[2][2];
  #pragma unroll
  for (int g = 0; g < 2; ++g)
    #pragma unroll
    for (int c = 0; c < 2; ++c)
      #pragma unroll
      for (int j = 0; j < 8; ++j)
        Qf[g][c][j] = qtb[(size_t)(c*32 + quad*8 + j)*SEQ + qw + g*16 + l15];

  bf16x8 ones;
  #pragma unroll
  for (int j = 0; j < 8; ++j) ones[j] = to_bf16(1.0f);

  f32x4 O[2][4] = {};
  f32x4 L[2] = {};

  bf16x8 kreg[2], vreg[2];
  // preload + stage tile 0 into buf 0
  #pragma unroll
  for (int c = 0; c < 2; ++c) {
    int row = c*32 + srow;
    kreg[c] = *(const bf16x8*)&krb[(size_t)row*HD + sch];
    vreg[c] = *(const bf16x8*)&vtb[(size_t)row*SEQ + sch];
  }
  #pragma unroll
  for (int c = 0; c < 2; ++c) {
    int row = c*32 + srow;
    *(bf16x8*)&K_lds[0][row*72 + sch] = kreg[c];
    *(bf16x8*)&V_lds[0][row*72 + sch] = vreg[c];
  }
  __syncthreads();

  for (int kt = 0; kt < 32; ++kt) {
    const int cur = kt & 1;
    // issue global prefetch for tile kt+1 (lands during compute)
    if (kt + 1 < 32) {
      #pragma unroll
      for (int c = 0; c < 2; ++c) {
        int row = c*32 + srow;
        kreg[c] = *(const bf16x8*)&krb[(size_t)((kt+1)*64 + row)*HD + sch];
        vreg[c] = *(const bf16x8*)&vtb[(size_t)row*SEQ + (kt+1)*64 + sch];
      }
    }

    bf16x8 ak[4][2], bv[4][2];
    #pragma unroll
    for (int nt = 0; nt < 4; ++nt) {
      ak[nt][0] = *(const bf16x8*)&K_lds[cur][(nt*16 + l15)*72 + quad*8];
      ak[nt][1] = *(const bf16x8*)&K_lds[cur][(nt*16 + l15)*72 + 32 + quad*8];
      bv[nt][0] = *(const bf16x8*)&V_lds[cur][(nt*16 + l15)*72 + quad*8];
      bv[nt][1] = *(const bf16x8*)&V_lds[cur][(nt*16 + l15)*72 + 32 + quad*8];
    }

    #pragma unroll
    for (int g = 0; g < 2; ++g) {
      // S^T tile: 64 keys x 16 q  (D: row=key=nt*16+quad*4+r, col=q=l15)
      f32x4 s[4] = {};
      __builtin_amdgcn_s_setprio(1);
      #pragma unroll
      for (int nt = 0; nt < 4; ++nt) {
        s[nt] = MFMA16(ak[nt][0], Qf[g][0], s[nt], 0, 0, 0);
        s[nt] = MFMA16(ak[nt][1], Qf[g][1], s[nt], 0, 0, 0);
      }
      __builtin_amdgcn_s_setprio(0);
      // exp2 (LOG2E folded upstream), pack 4 keys -> b64 write into P^T
      #pragma unroll
      for (int nt = 0; nt < 4; ++nt) {
        bf16x4 pk;
        #pragma unroll
        for (int r = 0; r < 4; ++r)
          pk[r] = to_bf16(__builtin_amdgcn_exp2f(s[nt][r]));
        *(bf16x4*)&P_lds[wave][l15*72 + nt*16 + quad*4] = pk;
      }
      // P^T A-fragments (m=q=l15, k=key contiguous)
      bf16x8 ap0 = *(const bf16x8*)&P_lds[wave][l15*72 + quad*8];
      bf16x8 ap1 = *(const bf16x8*)&P_lds[wave][l15*72 + 32 + quad*8];
      __builtin_amdgcn_s_setprio(1);
      #pragma unroll
      for (int nt = 0; nt < 4; ++nt) {
        O[g][nt] = MFMA16(ap0, bv[nt][0], O[g][nt], 0, 0, 0);
        O[g][nt] = MFMA16(ap1, bv[nt][1], O[g][nt], 0, 0, 0);
      }
      L[g] = MFMA16(ap0, ones, L[g], 0, 0, 0);   // row sums, same recurrence
      L[g] = MFMA16(ap1, ones, L[g], 0, 0, 0);
      __builtin_amdgcn_s_setprio(0);
    }

    // stage tile kt+1 into the other buffer, one barrier per tile
    if (kt + 1 < 32) {
      #pragma unroll
      for (int c = 0; c < 2; ++c) {
        int row = c*32 + srow;
        *(bf16x8*)&K_lds[cur^1][row*72 + sch] = kreg[c];
        *(bf16x8*)&V_lds[cur^1][row*72 + sch] = vreg[c];
      }
      __syncthreads();
    }
  }

  #pragma unroll
  for (int g = 0; g < 2; ++g)
    #pragma unroll
    for (int nt = 0; nt < 4; ++nt)
      #pragma unroll
      for (int r = 0; r < 4; ++r) {
        int qrow = qw + g*16 + quad*4 + r;
        float o = O[g][nt][r] / L[g][r];
        ctx[((size_t)b*SEQ + qrow)*DMODEL + h*HD + nt*16 + l15] = to_bf16(o);
      }
}

// ---------------------------------------------------------------------------
// K4: out = ctx @ out_w^T + bias. m-tile 128 x n-tile 64, BK=64, prefetch.
// ---------------------------------------------------------------------------
__global__ __launch_bounds__(256) void k4_proj(
    const bf16_t* __restrict__ ctx,    // [NB*SEQ][DMODEL] bf16
    const float* __restrict__ w,       // [DMODEL][DMODEL] fp32
    const float* __restrict__ bias,
    float* __restrict__ out)
{
  __shared__ __align__(16) bf16_t A_lds[128*72];
  __shared__ __align__(16) bf16_t B_lds[64*72];
  const int tid = threadIdx.x;
  const int blk = blockIdx.x;        // mt*16 + ntile
  const int n0 = (blk & 15) * 64;
  const int m0 = (blk >> 4) * 128;
  const int wave = tid >> 6, lane = tid & 63;
  const int l15 = lane & 15, quad = lane >> 4;
  const int ra = tid >> 1, ca = (tid & 1) * 32;     // A staging: 128 rows x 32
  const int rs = tid >> 2, cs = (tid & 3) * 16;     // W staging: 64 rows x 16

  f32x4 acc[2][4] = {};
  bf16x8 areg[4];
  float4 wreg[4];

  #pragma unroll
  for (int i = 0; i < 4; ++i) {
    areg[i] = *(const bf16x8*)&ctx[(size_t)(m0 + ra)*DMODEL + ca + i*8];
    wreg[i] = *(const float4*)&w[(size_t)(n0 + rs)*DMODEL + cs + i*4];
  }

  for (int it = 0; it < DMODEL/64; ++it) {
    if (it) __syncthreads();
    #pragma unroll
    for (int i = 0; i < 4; ++i)
      *(bf16x8*)&A_lds[ra*72 + ca + i*8] = areg[i];
    #pragma unroll
    for (int i = 0; i < 2; ++i) {
      bf16x8 wb;
      float4 wa = wreg[i*2], wc = wreg[i*2+1];
      wb[0]=to_bf16(wa.x); wb[1]=to_bf16(wa.y); wb[2]=to_bf16(wa.z); wb[3]=to_bf16(wa.w);
      wb[4]=to_bf16(wc.x); wb[5]=to_bf16(wc.y); wb[6]=to_bf16(wc.z); wb[7]=to_bf16(wc.w);
      *(bf16x8*)&B_lds[rs*72 + cs + i*8] = wb;
    }
    __syncthreads();
    if (it + 1 < DMODEL/64) {
      int kb = (it + 1) * 64;
      #pragma unroll
      for (int i = 0; i < 4; ++i) {
        areg[i] = *(const bf16x8*)&ctx[(size_t)(m0 + ra)*DMODEL + kb + ca + i*8];
        wreg[i] = *(const float4*)&w[(size_t)(n0 + rs)*DMODEL + kb + cs + i*4];
      }
    }
    #pragma unroll
    for (int kc = 0; kc < 2; ++kc) {
      const int off = kc*32 + quad*8;
      bf16x8 bfr[4];
      #pragma unroll
      for (int nt = 0; nt < 4; ++nt)
        bfr[nt] = *(const bf16x8*)&B_lds[(nt*16 + l15)*72 + off];
      #pragma unroll
      for (int g = 0; g < 2; ++g) {
        bf16x8 af = *(const bf16x8*)&A_lds[(wave*32 + g*16 + l15)*72 + off];
        #pragma unroll
        for (int nt = 0; nt < 4; ++nt)
          acc[g][nt] = MFMA16(af, bfr[nt], acc[g][nt], 0, 0, 0);
      }
    }
  }
  #pragma unroll
  for (int nt = 0; nt < 4; ++nt) {
    float bb = bias[n0 + nt*16 + l15];
    #pragma unroll
    for (int g = 0; g < 2; ++g)
      #pragma unroll
      for (int r = 0; r < 4; ++r)
        out[(size_t)(m0 + wave*32 + g*16 + quad*4 + r)*DMODEL + n0 + nt*16 + l15] =
            acc[g][nt][r] + bb;
  }
}

extern "C" void kernel_launch(void* const* d_in, const int* in_sizes, int n_in,
                              void* d_out, int out_size, void* d_ws, size_t ws_size,
                              hipStream_t stream)
{
  const float* q     = (const float*)d_in[0];
  const float* k     = (const float*)d_in[1];
  const float* v     = (const float*)d_in[2];
  const float* mask  = (const float*)d_in[3];
  const float* out_w = (const float*)d_in[4];
  const float* out_b = (const float*)d_in[5];
  float* out = (float*)d_out;

  const size_t elems = (size_t)NB * NH * SEQ * HD;
  bf16_t* qrT = (bf16_t*)d_ws;
  bf16_t* krN = qrT + elems;
  bf16_t* vT  = krN + elems;
  bf16_t* qtT = vT  + elems;
  bf16_t* ctx = qtT + elems;

  k1_rope_pack<<<dim3(NB*NH*(SEQ/64)), dim3(256), 0, stream>>>(q, k, v, qrT, krN, vT);
  k2_qt_gemm <<<dim3(NH*(SEQ/64)),     dim3(256), 0, stream>>>(mask, qrT, qtT);
  k3_flash   <<<dim3(NB*NH*(SEQ/128)), dim3(256), 0, stream>>>(qtT, krN, vT, ctx);
  k4_proj    <<<dim3((NB*SEQ/128)*(DMODEL/64)), dim3(256), 0, stream>>>(ctx, out_w, out_b, out);
}